// Round 7
// baseline (9148.792 us; speedup 1.0000x reference)
//
#include <hip/hip_runtime.h>
#include <hip/hip_bf16.h>
#include <stdint.h>

#define H_  10
#define B_  16384
#define F_  4
#define D_  2048
#define C_  2

typedef __attribute__((ext_vector_type(8)))  short  short8;
typedef __attribute__((ext_vector_type(16))) float  floatx16;

typedef const uint32_t __attribute__((address_space(1))) gu32;
typedef uint32_t       __attribute__((address_space(3))) lu32;

__device__ __forceinline__ void async16(const void* g, void* l) {
    __builtin_amdgcn_global_load_lds((gu32*)g, (lu32*)l, 16, 0, 0);
}

__device__ __forceinline__ short8 bc8(uint4 v) { return __builtin_bit_cast(short8, v); }

// relu + round-half-up bf16 pack (hot path, proven numerics)
__device__ __forceinline__ uint32_t packbf(float a, float b) {
    a = fmaxf(a, 0.f); b = fmaxf(b, 0.f);
    const uint32_t ax = __builtin_bit_cast(uint32_t, a) + 0x8000u;
    const uint32_t bx = __builtin_bit_cast(uint32_t, b) + 0x8000u;
    return (ax >> 16) | (bx & 0xFFFF0000u);
}

// full-precision RNE pack (convert kernel only)
__device__ __forceinline__ uint32_t f2bf(float f) {
    union { float f; uint32_t u; } a; a.f = f;
    uint32_t u = a.u;
    u += 0x7FFF + ((u >> 16) & 1);
    return u >> 16;
}
__device__ __forceinline__ uint32_t pack2bf(float a, float b) {
    return f2bf(a) | (f2bf(b) << 16);
}

// ---------------------------------------------------------------------------
// ws layout (bytes) — total 237,502,464 (proven in-budget R1-R6):
//   0          : Bc    bf16 [H][4096][2048] (n-major, k-contig; n<2048 = W21,
//                                            n>=2048 = W22)      167,772,160
//   167772160  : acc31 f32 [H][B_][C_]                             1,310,720
//   169082880  : acc32 f32 [H][B_][C_]                             1,310,720
//   170393600  : h1t   bf16 [B_][2048]  (per-head, reused)        67,108,864
// ---------------------------------------------------------------------------

__global__ __launch_bounds__(256) void k_convert(
    const float* __restrict__ W21, const float* __restrict__ W22,
    uint16_t* __restrict__ Bc)
{
    __shared__ float tile[64][65];
    const int z = blockIdx.z;
    const int h = z % H_;
    const float* src = (z < H_ ? W21 : W22) + (size_t)h * D_ * D_;
    uint16_t*   dst  = Bc + (size_t)h * 2 * D_ * D_ + (z < H_ ? 0 : (size_t)D_ * D_);
    const int k0 = blockIdx.x * 64, n0 = blockIdx.y * 64;
    const int t = threadIdx.x;

    const int c4 = (t & 15) * 4;
    const int rb = (t >> 4) * 4;
#pragma unroll
    for (int i = 0; i < 4; i++) {
        const float4 v = *(const float4*)(src + (size_t)(k0 + rb + i) * D_ + n0 + c4);
        tile[rb + i][c4 + 0] = v.x; tile[rb + i][c4 + 1] = v.y;
        tile[rb + i][c4 + 2] = v.z; tile[rb + i][c4 + 3] = v.w;
    }
    __syncthreads();
    const int n = t >> 2;
    const int cb = (t & 3) * 2;
#pragma unroll
    for (int j = 0; j < 2; j++) {
        const int kk = (cb + j) * 8;
        uint32_t pk[4];
#pragma unroll
        for (int e = 0; e < 4; e++)
            pk[e] = pack2bf(tile[kk + 2 * e][n], tile[kk + 2 * e + 1][n]);
        *(uint4*)(dst + (size_t)(n0 + n) * D_ + k0 + kk) = make_uint4(pk[0], pk[1], pk[2], pk[3]);
    }
}

__global__ __launch_bounds__(256) void k_zero(uint4* p, int n4) {
    const int i = blockIdx.x * 256 + threadIdx.x;
    if (i < n4) p[i] = make_uint4(0u, 0u, 0u, 0u);
}

// ---------------------------------------------------------------------------
// h1 = relu(x @ W1[h] + b1[h])  -> bf16 [B_][2048], row-major k-contig
// ---------------------------------------------------------------------------
__global__ __launch_bounds__(256) void k_h1(
    const float* __restrict__ x, const float* __restrict__ W1,
    const float* __restrict__ b1, uint16_t* __restrict__ h1t, int h)
{
    const int t = threadIdx.x;
    const int kc = t & 127;            // 16-wide k chunk
    const int rh = t >> 7;             // 0,1
    const int k0 = kc * 16;
    const float* W1h = W1 + (size_t)h * F_ * D_;
    float w[4][16], bb[16];
#pragma unroll
    for (int f = 0; f < 4; f++)
#pragma unroll
        for (int j = 0; j < 16; j += 4) {
            const float4 v = *(const float4*)(W1h + f * D_ + k0 + j);
            w[f][j] = v.x; w[f][j+1] = v.y; w[f][j+2] = v.z; w[f][j+3] = v.w;
        }
#pragma unroll
    for (int j = 0; j < 16; j += 4) {
        const float4 v = *(const float4*)(b1 + (size_t)h * D_ + k0 + j);
        bb[j] = v.x; bb[j+1] = v.y; bb[j+2] = v.z; bb[j+3] = v.w;
    }
    const int rowBase = blockIdx.x * 16 + rh * 8;
#pragma unroll
    for (int rr = 0; rr < 8; rr++) {
        const int row = rowBase + rr;
        const float4 xv = *(const float4*)(x + (size_t)row * 4);
        uint32_t pk[8];
#pragma unroll
        for (int j = 0; j < 16; j += 2) {
            float aa = fmaf(xv.x, w[0][j], bb[j]);
            aa = fmaf(xv.y, w[1][j], aa);
            aa = fmaf(xv.z, w[2][j], aa);
            aa = fmaf(xv.w, w[3][j], aa);
            float bv = fmaf(xv.x, w[0][j+1], bb[j+1]);
            bv = fmaf(xv.y, w[1][j+1], bv);
            bv = fmaf(xv.z, w[2][j+1], bv);
            bv = fmaf(xv.w, w[3][j+1], bv);
            pk[j >> 1] = packbf(aa, bv);
        }
        uint16_t* d = h1t + (size_t)row * D_ + k0;
        *(uint4*)d       = make_uint4(pk[0], pk[1], pk[2], pk[3]);
        *(uint4*)(d + 8) = make_uint4(pk[4], pk[5], pk[6], pk[7]);
    }
}

// ---------------------------------------------------------------------------
// BM=256 x BN=256, BK=64, 256 threads (4 waves 1Mx4N), 128 KB dynamic LDS.
// FAT-ITERATION design: per wave per K-iter = 64 MFMAs (2048 cyc matrix pipe)
// with ONE wave per SIMD — per-iter sync/latency (~700cyc) amortized by MFMA
// itself instead of by co-resident blocks. 1 block/CU (intentional; occupancy
// counter will read ~12%).
// A and B both LDS double-buffered (2x32 KB each) via global_load_lds, staged
// 2 K-tiles ahead; ONE manual vmcnt(16) + 2 barriers per iter; the hot loop
// has zero compiler-tracked VMEM loads (no conservative compiler waits).
// vmcnt(16): younger-than-stage(t) = stage(t+1) = 16 lane-loads. Tail clamps
// keep the count uniform (redundant tile-31 restages are harmless/post-read).
// LDS swizzle (uint4 units): unit = row*8 + (c ^ (row&7) ^ ((row>>3)&3)),
// linear dest + pre-swizzled global source (R6-proven, 0 conflicts).
// Read: u7 = (kk*2+hi) ^ (l31&7) ^ (l31>>3)  [row&7 == l31&7 for all frags].
// MFMA 32x32x16; per-wave 256x64 out = 8m x 2n frags. Epilogue = R3 verbatim
// (extended to 8 m-frags).
// ---------------------------------------------------------------------------
__global__ __launch_bounds__(256, 1) void k_gemm(
    const uint16_t* __restrict__ h1t, const uint16_t* __restrict__ Bcw,
    const float* __restrict__ b21, const float* __restrict__ b22,
    const float* __restrict__ W31, const float* __restrict__ W32,
    float* __restrict__ acc31, float* __restrict__ acc32, int h)
{
    extern __shared__ uint4 smem[];   // A: [0,4096) 2x2048, B: [4096,8192) 2x2048

    // bijective XCD swizzle: 1024 wgs; xcd owns m-tiles [xcd*8, xcd*8+8)
    const int bid = blockIdx.x;
    const int xcd = bid & 7, idx = bid >> 3;
    const int mt = xcd * 8 + (idx & 7), nt = idx >> 3;
    const int mBase = mt * 256, nBase = nt * 256;   // nBase in concat [0,4096)

    const int t = threadIdx.x;
    const int lane = t & 63, wid = t >> 6;          // 4 waves; wid = n-chunk
    const int l31 = lane & 31, hi = lane >> 5;

    // ---- staging: dest unit j*256+t (linear), source pre-swizzled
    const uint16_t* Abase = h1t + (size_t)mBase * D_;
    const uint16_t* Bbase = Bcw + (size_t)h * (4096 * (size_t)D_) + (size_t)nBase * D_;
    int soff[8];
#pragma unroll
    for (int j = 0; j < 8; j++) {
        const int unit = j * 256 + t;
        const int row = unit >> 3;
        const int cc = (unit & 7) ^ (row & 7) ^ ((row >> 3) & 3);
        soff[j] = row * D_ + cc * 8;
    }
    const int wbase = wid * 64;

    auto stageTile = [&](int buf, int kt) {
#pragma unroll
        for (int j = 0; j < 8; j++)
            async16(Abase + soff[j] + kt, smem + buf * 2048 + j * 256 + wbase);
#pragma unroll
        for (int j = 0; j < 8; j++)
            async16(Bbase + soff[j] + kt, smem + 4096 + buf * 2048 + j * 256 + wbase);
    };

    floatx16 acc[8][2];
#pragma unroll
    for (int mi = 0; mi < 8; mi++)
#pragma unroll
        for (int nj = 0; nj < 2; nj++)
#pragma unroll
            for (int e = 0; e < 16; e++) acc[mi][nj][e] = 0.f;

    const int x7 = l31 & 7, s3 = l31 >> 3;

    auto kIter = [&](int tt, int buf) {
        asm volatile("s_waitcnt vmcnt(16)" ::: "memory");   // tile tt fully landed
        __builtin_amdgcn_sched_barrier(0);
        __builtin_amdgcn_s_barrier();                       // all waves' stage visible
        const uint4* Ab = smem + buf * 2048;
        const uint4* Bb = smem + 4096 + buf * 2048;
#pragma unroll
        for (int kk = 0; kk < 4; kk++) {
            const int u7 = (kk * 2 + hi) ^ x7 ^ s3;
            short8 bf[2];
#pragma unroll
            for (int nj = 0; nj < 2; nj++)
                bf[nj] = bc8(Bb[(wbase + nj * 32 + l31) * 8 + u7]);
#pragma unroll
            for (int mi = 0; mi < 8; mi++) {
                const short8 af = bc8(Ab[(mi * 32 + l31) * 8 + u7]);
#pragma unroll
                for (int nj = 0; nj < 2; nj++)
                    acc[mi][nj] = __builtin_amdgcn_mfma_f32_32x32x16_bf16(
                        af, bf[nj], acc[mi][nj], 0, 0, 0);
            }
        }
        __builtin_amdgcn_s_barrier();                       // all reads of buf done
        __builtin_amdgcn_sched_barrier(0);
        stageTile(buf, ((tt < 30) ? tt + 2 : 31) * 64);     // tile tt+2 -> freed buf
    };

    // ---- prologue: tiles 0,1 in flight (32 loads); vmcnt(16) at iter 0
    stageTile(0, 0);
    stageTile(1, 64);

#pragma unroll 1
    for (int it = 0; it < 16; ++it) {
        kIter(2 * it,     0);
        kIter(2 * it + 1, 1);
    }

    // ---- Epilogue: bias + relu + (.)@W3[half] reduce over n, shuffle, atomics
    const int p    = nBase >> 11;          // 0: W21/W31 path, 1: W22/W32 path
    const int nloc = nBase & 2047;
    const float* b2p = (p ? b22 : b21) + (size_t)h * D_;
    const float* W3p = (p ? W32 : W31) + (size_t)h * D_ * C_;
    float* ab2 = (p ? acc32 : acc31) + (size_t)h * B_ * C_;

    float bs[2], w3x[2], w3y[2];
#pragma unroll
    for (int nj = 0; nj < 2; nj++) {
        const int e = nloc + wid * 64 + nj * 32 + l31;
        bs[nj] = b2p[e];
        const float2 w2 = *(const float2*)(W3p + e * 2);
        w3x[nj] = w2.x; w3y[nj] = w2.y;
    }
#pragma unroll
    for (int mi = 0; mi < 8; mi++)
#pragma unroll
        for (int r = 0; r < 16; r++) {
            const float v0 = fmaxf(acc[mi][0][r] + bs[0], 0.f);
            const float v1 = fmaxf(acc[mi][1][r] + bs[1], 0.f);
            float s0 = fmaf(v0, w3x[0], v1 * w3x[1]);
            float s1 = fmaf(v0, w3y[0], v1 * w3y[1]);
#pragma unroll
            for (int off = 1; off < 32; off <<= 1) {
                s0 += __shfl_xor(s0, off, 64);
                s1 += __shfl_xor(s1, off, 64);
            }
            if (l31 == 0) {
                const int row = mBase + mi * 32 + (r & 3) + 8 * (r >> 2) + 4 * hi;
                atomicAdd(&ab2[row * C_ + 0], s0);
                atomicAdd(&ab2[row * C_ + 1], s1);
            }
        }
}

// ---------------------------------------------------------------------------
// Finalize: biases, sigmoid head, CBF-QP correction, softmax-weighted mix
// ---------------------------------------------------------------------------
__global__ __launch_bounds__(256) void k_final(
    const float* __restrict__ x,
    const float* __restrict__ acc31, const float* __restrict__ acc32,
    const float* __restrict__ b31, const float* __restrict__ b32,
    const float* __restrict__ wt, const float* __restrict__ mean,
    const float* __restrict__ stdv, float* __restrict__ out)
{
    const int b = blockIdx.x * 256 + threadIdx.x;
    const float4 xb = *(const float4*)(x + (size_t)b * 4);
    const float px = xb.x * stdv[0] + mean[0];
    const float py = xb.y * stdv[1] + mean[1];
    const float th = xb.z * stdv[2] + mean[2];
    const float v  = xb.w * stdv[3] + mean[3];
    const float dx = px - 40.0f, dy = py - 15.0f;
    const float st = sinf(th), ct = cosf(th);
    const float barrier = dx * dx + dy * dy - 36.0f;
    const float bdot = 2.f * dx * v * ct + 2.f * dy * v * st;
    const float Lf2b = 2.f * v * v;
    const float G0 = -(-2.f * dx * v * st + 2.f * dy * v * ct);
    const float G1 = -(2.f * dx * ct + 2.f * dy * st);
    const float GG = G0 * G0 + G1 * G1;

    float we[H_];
    float wmax = wt[0];
    for (int h = 1; h < H_; h++) wmax = fmaxf(wmax, wt[h]);
    float wsum = 0.f;
    for (int h = 0; h < H_; h++) { we[h] = expf(wt[h] - wmax); wsum += we[h]; }

    float o0 = 0.f, o1 = 0.f;
#pragma unroll
    for (int h = 0; h < H_; h++) {
        const size_t idx = ((size_t)h * B_ + b) * 2;
        const float x310 = acc31[idx]     + b31[h * 2];
        const float x311 = acc31[idx + 1] + b31[h * 2 + 1];
        const float z0 = acc32[idx]     + b32[h * 2];
        const float z1 = acc32[idx + 1] + b32[h * 2 + 1];
        const float x320 = 4.f / (1.f + expf(-z0));
        const float x321 = 4.f / (1.f + expf(-z1));
        const float hr = Lf2b + (x320 + x321) * bdot + x320 * x321 * barrier;
        const float Gu = G0 * x310 + G1 * x311;
        const float lam = fmaxf(Gu - hr, 0.f) / GG;
        o0 += we[h] * (x310 - lam * G0);
        o1 += we[h] * (x311 - lam * G1);
    }
    out[b * 2]     = o0 / wsum;
    out[b * 2 + 1] = o1 / wsum;
}

extern "C" void kernel_launch(void* const* d_in, const int* in_sizes, int n_in,
                              void* d_out, int out_size, void* d_ws, size_t ws_size,
                              hipStream_t stream)
{
    const float* x    = (const float*)d_in[0];
    const float* W1   = (const float*)d_in[1];
    const float* b1   = (const float*)d_in[2];
    const float* W21  = (const float*)d_in[3];
    const float* b21  = (const float*)d_in[4];
    const float* W22  = (const float*)d_in[5];
    const float* b22  = (const float*)d_in[6];
    const float* W31  = (const float*)d_in[7];
    const float* b31  = (const float*)d_in[8];
    const float* W32  = (const float*)d_in[9];
    const float* b32  = (const float*)d_in[10];
    const float* wt   = (const float*)d_in[11];
    const float* mean = (const float*)d_in[12];
    const float* stdv = (const float*)d_in[13];
    float* out = (float*)d_out;

    char* ws = (char*)d_ws;
    uint16_t* Bc   = (uint16_t*)(ws);
    float* acc31   = (float*)(ws + 167772160);
    float* acc32   = (float*)(ws + 169082880);
    uint16_t* h1t  = (uint16_t*)(ws + 170393600);

    static bool attr_done = false;
    if (!attr_done) {
        hipFuncSetAttribute(reinterpret_cast<const void*>(k_gemm),
                            hipFuncAttributeMaxDynamicSharedMemorySize, 131072);
        attr_done = true;
    }

    k_convert<<<dim3(32, 32, 20), 256, 0, stream>>>(W21, W22, Bc);
    k_zero<<<dim3(640), 256, 0, stream>>>((uint4*)acc31, 163840);
    for (int h = 0; h < H_; ++h) {
        k_h1<<<dim3(1024), 256, 0, stream>>>(x, W1, b1, h1t, h);
        k_gemm<<<dim3(1024), 256, 131072, stream>>>(h1t, Bc, b21, b22, W31, W32,
                                                    acc31, acc32, h);
    }
    k_final<<<dim3(64), 256, 0, stream>>>(x, acc31, acc32, b31, b32, wt, mean, stdv, out);
}

// Round 8
// 3630.584 us; speedup vs baseline: 2.5199x; 2.5199x over previous
//
#include <hip/hip_runtime.h>
#include <hip/hip_bf16.h>
#include <stdint.h>

#define H_  10
#define B_  16384
#define F_  4
#define D_  2048
#define C_  2

typedef __attribute__((ext_vector_type(8)))  short  short8;
typedef __attribute__((ext_vector_type(16))) float  floatx16;

typedef const uint32_t __attribute__((address_space(1))) gu32;
typedef uint32_t       __attribute__((address_space(3))) lu32;

__device__ __forceinline__ void async16(const void* g, void* l) {
    __builtin_amdgcn_global_load_lds((gu32*)g, (lu32*)l, 16, 0, 0);
}

__device__ __forceinline__ short8 bc8(uint4 v) { return __builtin_bit_cast(short8, v); }

// relu + round-half-up bf16 pack (hot path, proven numerics)
__device__ __forceinline__ uint32_t packbf(float a, float b) {
    a = fmaxf(a, 0.f); b = fmaxf(b, 0.f);
    const uint32_t ax = __builtin_bit_cast(uint32_t, a) + 0x8000u;
    const uint32_t bx = __builtin_bit_cast(uint32_t, b) + 0x8000u;
    return (ax >> 16) | (bx & 0xFFFF0000u);
}

// full-precision RNE pack (convert kernel only)
__device__ __forceinline__ uint32_t f2bf(float f) {
    union { float f; uint32_t u; } a; a.f = f;
    uint32_t u = a.u;
    u += 0x7FFF + ((u >> 16) & 1);
    return u >> 16;
}
__device__ __forceinline__ uint32_t pack2bf(float a, float b) {
    return f2bf(a) | (f2bf(b) << 16);
}

// ---------------------------------------------------------------------------
// ws layout (bytes) — total 237,502,464 (proven in-budget R1-R7):
//   0          : Bc    bf16 [H][4096][2048] (n-major, k-contig; n<2048 = W21,
//                                            n>=2048 = W22)      167,772,160
//   167772160  : acc31 f32 [H][B_][C_]                             1,310,720
//   169082880  : acc32 f32 [H][B_][C_]                             1,310,720
//   170393600  : h1t   bf16 [B_][2048]  (per-head, reused)        67,108,864
// ---------------------------------------------------------------------------

__global__ __launch_bounds__(256) void k_convert(
    const float* __restrict__ W21, const float* __restrict__ W22,
    uint16_t* __restrict__ Bc)
{
    __shared__ float tile[64][65];
    const int z = blockIdx.z;
    const int h = z % H_;
    const float* src = (z < H_ ? W21 : W22) + (size_t)h * D_ * D_;
    uint16_t*   dst  = Bc + (size_t)h * 2 * D_ * D_ + (z < H_ ? 0 : (size_t)D_ * D_);
    const int k0 = blockIdx.x * 64, n0 = blockIdx.y * 64;
    const int t = threadIdx.x;

    const int c4 = (t & 15) * 4;
    const int rb = (t >> 4) * 4;
#pragma unroll
    for (int i = 0; i < 4; i++) {
        const float4 v = *(const float4*)(src + (size_t)(k0 + rb + i) * D_ + n0 + c4);
        tile[rb + i][c4 + 0] = v.x; tile[rb + i][c4 + 1] = v.y;
        tile[rb + i][c4 + 2] = v.z; tile[rb + i][c4 + 3] = v.w;
    }
    __syncthreads();
    const int n = t >> 2;
    const int cb = (t & 3) * 2;
#pragma unroll
    for (int j = 0; j < 2; j++) {
        const int kk = (cb + j) * 8;
        uint32_t pk[4];
#pragma unroll
        for (int e = 0; e < 4; e++)
            pk[e] = pack2bf(tile[kk + 2 * e][n], tile[kk + 2 * e + 1][n]);
        *(uint4*)(dst + (size_t)(n0 + n) * D_ + k0 + kk) = make_uint4(pk[0], pk[1], pk[2], pk[3]);
    }
}

__global__ __launch_bounds__(256) void k_zero(uint4* p, int n4) {
    const int i = blockIdx.x * 256 + threadIdx.x;
    if (i < n4) p[i] = make_uint4(0u, 0u, 0u, 0u);
}

// ---------------------------------------------------------------------------
// h1 = relu(x @ W1[h] + b1[h])  -> bf16 [B_][2048], row-major k-contig
// ---------------------------------------------------------------------------
__global__ __launch_bounds__(256) void k_h1(
    const float* __restrict__ x, const float* __restrict__ W1,
    const float* __restrict__ b1, uint16_t* __restrict__ h1t, int h)
{
    const int t = threadIdx.x;
    const int kc = t & 127;            // 16-wide k chunk
    const int rh = t >> 7;             // 0,1
    const int k0 = kc * 16;
    const float* W1h = W1 + (size_t)h * F_ * D_;
    float w[4][16], bb[16];
#pragma unroll
    for (int f = 0; f < 4; f++)
#pragma unroll
        for (int j = 0; j < 16; j += 4) {
            const float4 v = *(const float4*)(W1h + f * D_ + k0 + j);
            w[f][j] = v.x; w[f][j+1] = v.y; w[f][j+2] = v.z; w[f][j+3] = v.w;
        }
#pragma unroll
    for (int j = 0; j < 16; j += 4) {
        const float4 v = *(const float4*)(b1 + (size_t)h * D_ + k0 + j);
        bb[j] = v.x; bb[j+1] = v.y; bb[j+2] = v.z; bb[j+3] = v.w;
    }
    const int rowBase = blockIdx.x * 16 + rh * 8;
#pragma unroll
    for (int rr = 0; rr < 8; rr++) {
        const int row = rowBase + rr;
        const float4 xv = *(const float4*)(x + (size_t)row * 4);
        uint32_t pk[8];
#pragma unroll
        for (int j = 0; j < 16; j += 2) {
            float aa = fmaf(xv.x, w[0][j], bb[j]);
            aa = fmaf(xv.y, w[1][j], aa);
            aa = fmaf(xv.z, w[2][j], aa);
            aa = fmaf(xv.w, w[3][j], aa);
            float bv = fmaf(xv.x, w[0][j+1], bb[j+1]);
            bv = fmaf(xv.y, w[1][j+1], bv);
            bv = fmaf(xv.z, w[2][j+1], bv);
            bv = fmaf(xv.w, w[3][j+1], bv);
            pk[j >> 1] = packbf(aa, bv);
        }
        uint16_t* d = h1t + (size_t)row * D_ + k0;
        *(uint4*)d       = make_uint4(pk[0], pk[1], pk[2], pk[3]);
        *(uint4*)(d + 8) = make_uint4(pk[4], pk[5], pk[6], pk[7]);
    }
}

// ---------------------------------------------------------------------------
// BM=128 x BN=128, BK=64, 256 threads (4 waves 2Mx2N), 32 KB static LDS,
// single-buffered, R3's exact sync structure. Per-wave 64x64 out = 2m x 2n
// frags of 32x32 -> acc = 64 AGPR; launch_bounds(256,4) caps 128 regs/thread
// -> 4 blocks/CU co-resident (16 waves/CU, 4/SIMD): each block's exposed
// vmcnt(0) stage drain is covered by 3 sibling blocks' compute (R3 had 1).
// LDS swizzle (uint4 units): unit = row*8 + (c ^ (row&7) ^ ((row>>3)&3)),
// linear gload_lds dest + pre-swizzled global source (R6-proven, 0 conflict).
// Read: u7 = (kk*2+hi) ^ (l31&7) ^ (l31>>3)  [row&7==l31&7, (row>>3)&3==l31>>3
// since all frag row bases are multiples of 32].
// MFMA 32x32x16. Epilogue = R3 pattern (2 m-frags). Grid 4096/head, XCD-swz.
// ---------------------------------------------------------------------------
__global__ __launch_bounds__(256, 4) void k_gemm(
    const uint16_t* __restrict__ h1t, const uint16_t* __restrict__ Bcw,
    const float* __restrict__ b21, const float* __restrict__ b22,
    const float* __restrict__ W31, const float* __restrict__ W32,
    float* __restrict__ acc31, float* __restrict__ acc32, int h)
{
    __shared__ uint4 smem[2048];   // A: [0,1024), B: [1024,2048)

    // XCD-contiguous M-slice: xcd owns m-tiles [xcd*16, xcd*16+16), sweeps n
    const int bid = blockIdx.x;
    const int xcd = bid & 7, idx = bid >> 3;           // idx in [0,512)
    const int mt = xcd * 16 + (idx & 15), nt = idx >> 4;   // nt in [0,32)
    const int mBase = mt * 128, nBase = nt * 128;      // nBase in concat [0,4096)

    const int t = threadIdx.x;
    const int lane = t & 63, wid = t >> 6;             // 4 waves: 2m x 2n
    const int l31 = lane & 31, hi = lane >> 5;
    const int wm = wid >> 1, wn = wid & 1;

    // ---- staging: dest unit j*256+t (linear), source pre-swizzled (shared A/B)
    const uint16_t* Abase = h1t + (size_t)mBase * D_;
    const uint16_t* Bbase = Bcw + (size_t)h * (4096 * (size_t)D_) + (size_t)nBase * D_;
    int soff[4];
#pragma unroll
    for (int j = 0; j < 4; j++) {
        const int unit = j * 256 + t;
        const int row = unit >> 3;
        const int cc = (unit & 7) ^ (row & 7) ^ ((row >> 3) & 3);
        soff[j] = row * D_ + cc * 8;
    }
    const int wbase = wid * 64;

    floatx16 acc[2][2];
#pragma unroll
    for (int mi = 0; mi < 2; mi++)
#pragma unroll
        for (int nj = 0; nj < 2; nj++)
#pragma unroll
            for (int e = 0; e < 16; e++) acc[mi][nj][e] = 0.f;

    const int x7 = l31 & 7, s3 = l31 >> 3;

    for (int kt = 0; kt < D_; kt += 64) {
        // ---- stage A (16 KB) + B (16 KB), linear dest, pre-swizzled source
#pragma unroll
        for (int j = 0; j < 4; j++)
            async16(Abase + soff[j] + kt, smem + j * 256 + wbase);
#pragma unroll
        for (int j = 0; j < 4; j++)
            async16(Bbase + soff[j] + kt, smem + 1024 + j * 256 + wbase);
        asm volatile("s_waitcnt vmcnt(0)" ::: "memory");
        __builtin_amdgcn_sched_barrier(0);
        __builtin_amdgcn_s_barrier();

        // ---- compute: 4 k-steps of K=16, 4 MFMAs each
        __builtin_amdgcn_s_setprio(1);
#pragma unroll
        for (int kk = 0; kk < 4; kk++) {
            const int u7 = (kk * 2 + hi) ^ x7 ^ s3;
            short8 af[2], bf[2];
#pragma unroll
            for (int mi = 0; mi < 2; mi++)
                af[mi] = bc8(smem[(wm * 64 + mi * 32 + l31) * 8 + u7]);
#pragma unroll
            for (int nj = 0; nj < 2; nj++)
                bf[nj] = bc8(smem[1024 + (wn * 64 + nj * 32 + l31) * 8 + u7]);
#pragma unroll
            for (int mi = 0; mi < 2; mi++)
#pragma unroll
                for (int nj = 0; nj < 2; nj++)
                    acc[mi][nj] = __builtin_amdgcn_mfma_f32_32x32x16_bf16(
                        af[mi], bf[nj], acc[mi][nj], 0, 0, 0);
        }
        __builtin_amdgcn_s_setprio(0);
        __syncthreads();   // reads drained before next stage overwrites
    }

    // ---- Epilogue: bias + relu + (.)@W3[half] reduce over n, shuffle, atomics
    const int p    = nBase >> 11;          // 0: W21/W31 path, 1: W22/W32 path
    const int nloc = nBase & 2047;
    const float* b2p = (p ? b22 : b21) + (size_t)h * D_;
    const float* W3p = (p ? W32 : W31) + (size_t)h * D_ * C_;
    float* ab2 = (p ? acc32 : acc31) + (size_t)h * B_ * C_;

    float bs[2], w3x[2], w3y[2];
#pragma unroll
    for (int nj = 0; nj < 2; nj++) {
        const int e = nloc + wn * 64 + nj * 32 + l31;
        bs[nj] = b2p[e];
        const float2 w2 = *(const float2*)(W3p + e * 2);
        w3x[nj] = w2.x; w3y[nj] = w2.y;
    }
#pragma unroll
    for (int mi = 0; mi < 2; mi++)
#pragma unroll
        for (int r = 0; r < 16; r++) {
            const float v0 = fmaxf(acc[mi][0][r] + bs[0], 0.f);
            const float v1 = fmaxf(acc[mi][1][r] + bs[1], 0.f);
            float s0 = fmaf(v0, w3x[0], v1 * w3x[1]);
            float s1 = fmaf(v0, w3y[0], v1 * w3y[1]);
#pragma unroll
            for (int off = 1; off < 32; off <<= 1) {
                s0 += __shfl_xor(s0, off, 64);
                s1 += __shfl_xor(s1, off, 64);
            }
            if (l31 == 0) {
                const int row = mBase + wm * 64 + mi * 32 + (r & 3) + 8 * (r >> 2) + 4 * hi;
                atomicAdd(&ab2[row * C_ + 0], s0);
                atomicAdd(&ab2[row * C_ + 1], s1);
            }
        }
}

// ---------------------------------------------------------------------------
// Finalize: biases, sigmoid head, CBF-QP correction, softmax-weighted mix
// ---------------------------------------------------------------------------
__global__ __launch_bounds__(256) void k_final(
    const float* __restrict__ x,
    const float* __restrict__ acc31, const float* __restrict__ acc32,
    const float* __restrict__ b31, const float* __restrict__ b32,
    const float* __restrict__ wt, const float* __restrict__ mean,
    const float* __restrict__ stdv, float* __restrict__ out)
{
    const int b = blockIdx.x * 256 + threadIdx.x;
    const float4 xb = *(const float4*)(x + (size_t)b * 4);
    const float px = xb.x * stdv[0] + mean[0];
    const float py = xb.y * stdv[1] + mean[1];
    const float th = xb.z * stdv[2] + mean[2];
    const float v  = xb.w * stdv[3] + mean[3];
    const float dx = px - 40.0f, dy = py - 15.0f;
    const float st = sinf(th), ct = cosf(th);
    const float barrier = dx * dx + dy * dy - 36.0f;
    const float bdot = 2.f * dx * v * ct + 2.f * dy * v * st;
    const float Lf2b = 2.f * v * v;
    const float G0 = -(-2.f * dx * v * st + 2.f * dy * v * ct);
    const float G1 = -(2.f * dx * ct + 2.f * dy * st);
    const float GG = G0 * G0 + G1 * G1;

    float we[H_];
    float wmax = wt[0];
    for (int h = 1; h < H_; h++) wmax = fmaxf(wmax, wt[h]);
    float wsum = 0.f;
    for (int h = 0; h < H_; h++) { we[h] = expf(wt[h] - wmax); wsum += we[h]; }

    float o0 = 0.f, o1 = 0.f;
#pragma unroll
    for (int h = 0; h < H_; h++) {
        const size_t idx = ((size_t)h * B_ + b) * 2;
        const float x310 = acc31[idx]     + b31[h * 2];
        const float x311 = acc31[idx + 1] + b31[h * 2 + 1];
        const float z0 = acc32[idx]     + b32[h * 2];
        const float z1 = acc32[idx + 1] + b32[h * 2 + 1];
        const float x320 = 4.f / (1.f + expf(-z0));
        const float x321 = 4.f / (1.f + expf(-z1));
        const float hr = Lf2b + (x320 + x321) * bdot + x320 * x321 * barrier;
        const float Gu = G0 * x310 + G1 * x311;
        const float lam = fmaxf(Gu - hr, 0.f) / GG;
        o0 += we[h] * (x310 - lam * G0);
        o1 += we[h] * (x311 - lam * G1);
    }
    out[b * 2]     = o0 / wsum;
    out[b * 2 + 1] = o1 / wsum;
}

extern "C" void kernel_launch(void* const* d_in, const int* in_sizes, int n_in,
                              void* d_out, int out_size, void* d_ws, size_t ws_size,
                              hipStream_t stream)
{
    const float* x    = (const float*)d_in[0];
    const float* W1   = (const float*)d_in[1];
    const float* b1   = (const float*)d_in[2];
    const float* W21  = (const float*)d_in[3];
    const float* b21  = (const float*)d_in[4];
    const float* W22  = (const float*)d_in[5];
    const float* b22  = (const float*)d_in[6];
    const float* W31  = (const float*)d_in[7];
    const float* b31  = (const float*)d_in[8];
    const float* W32  = (const float*)d_in[9];
    const float* b32  = (const float*)d_in[10];
    const float* wt   = (const float*)d_in[11];
    const float* mean = (const float*)d_in[12];
    const float* stdv = (const float*)d_in[13];
    float* out = (float*)d_out;

    char* ws = (char*)d_ws;
    uint16_t* Bc   = (uint16_t*)(ws);
    float* acc31   = (float*)(ws + 167772160);
    float* acc32   = (float*)(ws + 169082880);
    uint16_t* h1t  = (uint16_t*)(ws + 170393600);

    k_convert<<<dim3(32, 32, 20), 256, 0, stream>>>(W21, W22, Bc);
    k_zero<<<dim3(640), 256, 0, stream>>>((uint4*)acc31, 163840);
    for (int h = 0; h < H_; ++h) {
        k_h1<<<dim3(1024), 256, 0, stream>>>(x, W1, b1, h1t, h);
        k_gemm<<<dim3(4096), 256, 0, stream>>>(h1t, Bc, b21, b22, W31, W32,
                                               acc31, acc32, h);
    }
    k_final<<<dim3(64), 256, 0, stream>>>(x, acc31, acc32, b31, b32, wt, mean, stdv, out);
}